// Round 3
// baseline (700.954 us; speedup 1.0000x reference)
//
#include <hip/hip_runtime.h>

typedef unsigned short ushort_t;
typedef __attribute__((ext_vector_type(8))) short short8;   // 8 bf16 = 4 VGPRs (MFMA A/B frag)
typedef __attribute__((ext_vector_type(4))) short short4v;  // 4 bf16 = 8B
typedef __attribute__((ext_vector_type(4))) float f32x4;    // MFMA C/D frag

#define NN 50000
#define EE 500000
#define DD 128
#define MAXT 10.0f

#define MFMA(a,b,c) __builtin_amdgcn_mfma_f32_16x16x32_bf16((a),(b),(c),0,0,0)

__device__ __forceinline__ ushort_t f2bf(float x){          // RNE float->bf16
  unsigned u = __float_as_uint(x);
  u += 0x7FFFu + ((u>>16)&1u);
  return (ushort_t)(u>>16);
}
__device__ __forceinline__ float sigm(float x){ return 1.0f/(1.0f+__expf(-x)); }
__device__ __forceinline__ float siluf(float x){ return x*sigm(x); }
__device__ __forceinline__ float clamp10(float x){ return fminf(fmaxf(x,-MAXT),MAXT); }

// load 8 consecutive fp32, convert to bf16x8 frag
__device__ __forceinline__ short8 ldcvt(const float* p){
  f32x4 x = *(const f32x4*)p;
  f32x4 y = *(const f32x4*)(p+4);
  short8 t;
  #pragma unroll
  for (int j=0;j<4;++j){ t[j]=(short)f2bf(x[j]); t[j+4]=(short)f2bf(y[j]); }
  return t;
}

// ---------------------------------------------------------------------------
// Weight prep: bf16, transposed to [n][k], XOR-swizzled rows.
// sigma-permute k for mats whose A-side comes from C-layout packs:
//   kidx = 8*(c&15) + (c>>4).
// mats: 0 W1a(nat)  1 W1b(nat)  2 W2(nat)  3 Wc1(sigma)  4 Wn1a(nat)
//       5 Wn1b(nat) 6 Wn2(sigma)
// ---------------------------------------------------------------------------
__global__ void k_prep(const float* __restrict__ We1, const float* __restrict__ We2,
                       const float* __restrict__ Wc1, const float* __restrict__ Wn1,
                       const float* __restrict__ Wn2, ushort_t* __restrict__ wpre)
{
  int idx = blockIdx.x*256 + threadIdx.x;
  if (idx >= 7*16384) return;
  int mat = idx >> 14;
  int loc = idx & 16383;
  int n = loc >> 7;
  int kidx = loc & 127;
  int ko = 16*(kidx&7) + (kidx>>3);
  float v;
  switch(mat){
    case 0: v = We1[kidx*DD + n]; break;
    case 1: v = We1[(128+kidx)*DD + n]; break;
    case 2: v = We2[kidx*DD + n]; break;           // natural
    case 3: v = Wc1[ko*DD + n]; break;             // sigma
    case 4: v = Wn1[kidx*DD + n]; break;
    case 5: v = Wn1[(128+kidx)*DD + n]; break;
    default: v = Wn2[ko*DD + n]; break;            // sigma
  }
  int byteoff = n*256 + ((kidx*2) ^ ((n&7)<<4));   // XOR swizzle (16B granule)
  *(ushort_t*)((char*)wpre + (size_t)mat*32768 + byteoff) = f2bf(v);
}

// ---------------------------------------------------------------------------
// CSR build (parallel scan; bsum/boff alias the csr buffer, overwritten later)
// ---------------------------------------------------------------------------
__global__ void k_count(const int* __restrict__ eidx, int* __restrict__ cnt){
  int e = blockIdx.x*256 + threadIdx.x;
  if (e < EE) atomicAdd(&cnt[eidx[e]], 1);
}
#define SCAN_B 196
__global__ void k_bsum(const int* __restrict__ cnt, int* __restrict__ bsum){
  __shared__ int sh[256];
  int t = threadIdx.x;
  int i = blockIdx.x*256 + t;
  sh[t] = (i < NN) ? cnt[i] : 0;
  __syncthreads();
  for (int off=128; off>0; off>>=1){
    if (t < off) sh[t] += sh[t+off];
    __syncthreads();
  }
  if (t==0) bsum[blockIdx.x] = sh[0];
}
__global__ void k_bscan(const int* __restrict__ bsum, int* __restrict__ boff){
  __shared__ int sh[256];
  int t = threadIdx.x;
  sh[t] = (t < SCAN_B) ? bsum[t] : 0;
  __syncthreads();
  for (int off=1; off<256; off<<=1){
    int x = (t>=off) ? sh[t-off] : 0;
    __syncthreads();
    sh[t] += x;
    __syncthreads();
  }
  if (t < SCAN_B) boff[t] = (t>0) ? sh[t-1] : 0;
}
__global__ void k_rscan(const int* __restrict__ cnt, const int* __restrict__ boff,
                        int* __restrict__ rowstart, int* __restrict__ cursor){
  __shared__ int sh[256];
  int t = threadIdx.x;
  int i = blockIdx.x*256 + t;
  int v = (i < NN) ? cnt[i] : 0;
  sh[t] = v;
  __syncthreads();
  for (int off=1; off<256; off<<=1){
    int x = (t>=off) ? sh[t-off] : 0;
    __syncthreads();
    sh[t] += x;
    __syncthreads();
  }
  int excl = sh[t] - v + boff[blockIdx.x];
  if (i < NN){ rowstart[i] = excl; cursor[i] = excl; }
  if (i == 0) rowstart[NN] = EE;
}
__global__ void k_scatter(const int* __restrict__ eidx, int* __restrict__ cursor,
                          int* __restrict__ csr){
  int e = blockIdx.x*256 + threadIdx.x;
  if (e < EE){
    int p = atomicAdd(&cursor[eidx[e]], 1);
    csr[p] = e;
  }
}

// ---------------------------------------------------------------------------
// GEMM helpers: wave tile = 32 rows x 64 cols x K=128.
// ---------------------------------------------------------------------------
__device__ __forceinline__ void stage(const ushort_t* __restrict__ wpre, int mat,
                                      ushort_t* Wbuf, int tid)
{
  const f32x4* src = (const f32x4*)(wpre + (size_t)mat*16384);
  f32x4* dst = (f32x4*)Wbuf;
  #pragma unroll
  for (int i=0;i<4;++i) dst[tid + 512*i] = src[tid + 512*i];
}
__device__ __forceinline__ void zacc(f32x4 acc[2][4]){
  #pragma unroll
  for (int i=0;i<2;++i)
    #pragma unroll
    for (int j=0;j<4;++j) acc[i][j] = (f32x4){0.f,0.f,0.f,0.f};
}
__device__ __forceinline__ void gemm_b16(const short8 af[2][4], const ushort_t* Wbuf,
                                         int cbase, int q, int s, f32x4 acc[2][4])
{
  #pragma unroll
  for (int kc=0;kc<4;++kc){
    const int koff = ((kc*64+q*16) ^ ((s&7)<<4));
    #pragma unroll
    for (int ct=0;ct<4;++ct){
      short8 bf = *(const short8*)((const char*)Wbuf + (cbase+ct*16+s)*256 + koff);
      acc[0][ct] = MFMA(af[0][kc],bf,acc[0][ct]);
      acc[1][ct] = MFMA(af[1][kc],bf,acc[1][ct]);
    }
  }
}
__device__ __forceinline__ void gemm_lds16(const ushort_t* ebuf, const ushort_t* Wbuf,
                                           int mbase, int cbase, int q, int s,
                                           f32x4 acc[2][4])
{
  #pragma unroll
  for (int kc=0;kc<4;++kc){
    const int koff = ((kc*64+q*16) ^ ((s&7)<<4));
    short8 a0 = *(const short8*)((const char*)ebuf + (mbase+s)*256 + koff);
    short8 a1 = *(const short8*)((const char*)ebuf + (mbase+16+s)*256 + koff);
    #pragma unroll
    for (int ct=0;ct<4;++ct){
      short8 bf = *(const short8*)((const char*)Wbuf + (cbase+ct*16+s)*256 + koff);
      acc[0][ct] = MFMA(a0,bf,acc[0][ct]);
      acc[1][ct] = MFMA(a1,bf,acc[1][ct]);
    }
  }
}

// ---------------------------------------------------------------------------
// H1 precompute: H1a = h@W1a + be1 ; H1b = h@W1b   (fp32 out, N x 128 each)
// ---------------------------------------------------------------------------
__launch_bounds__(512,4)
__global__ void k_pre1(const float* __restrict__ h,
                       const ushort_t* __restrict__ wpre,
                       const float* __restrict__ be1,
                       float* __restrict__ H1a, float* __restrict__ H1b)
{
  __shared__ ushort_t Wbuf[16384];
  const int tid = threadIdx.x;
  const int wv = tid>>6, ln = tid&63;
  const int wm = wv&3, wn = wv>>2;
  const int q = ln>>4, s = ln&15;
  const int cbase = wn*64;
  const int n0 = blockIdx.x*128;
  const int mb = wm*32;
  const int nd0 = min(n0 + mb + s,      NN-1);
  const int nd1 = min(n0 + mb + 16 + s, NN-1);

  f32x4 acc[2][4];
  short8 af[2][4];
  zacc(acc);
  #pragma unroll
  for (int kc=0;kc<4;++kc){
    af[0][kc] = ldcvt(h + (size_t)nd0*DD + kc*32 + q*8);
    af[1][kc] = ldcvt(h + (size_t)nd1*DD + kc*32 + q*8);
  }
  stage(wpre, 0, Wbuf, tid);
  __syncthreads();
  gemm_b16(af, Wbuf, cbase, q, s, acc);
  {
    float bb[4];
    #pragma unroll
    for (int ct=0;ct<4;++ct) bb[ct]=be1[cbase+16*ct+s];
    #pragma unroll
    for (int mt=0;mt<2;++mt)
      #pragma unroll
      for (int r=0;r<4;++r){
        int n = n0 + mb + mt*16 + q*4 + r;
        if (n < NN){
          float* op = H1a + (size_t)n*DD + cbase + s;
          #pragma unroll
          for (int ct=0;ct<4;++ct) op[16*ct] = acc[mt][ct][r] + bb[ct];
        }
      }
  }
  zacc(acc);
  __syncthreads();
  stage(wpre, 1, Wbuf, tid);
  __syncthreads();
  gemm_b16(af, Wbuf, cbase, q, s, acc);
  {
    #pragma unroll
    for (int mt=0;mt<2;++mt)
      #pragma unroll
      for (int r=0;r<4;++r){
        int n = n0 + mb + mt*16 + q*4 + r;
        if (n < NN){
          float* op = H1b + (size_t)n*DD + cbase + s;
          #pragma unroll
          for (int ct=0;ct<4;++ct) op[16*ct] = acc[mt][ct][r];
        }
      }
  }
}

// ---------------------------------------------------------------------------
// Edge kernel (CSR-sorted order): 128 edges/block, 8 waves 4(M) x 2(N).
// e1 = silu(H1a[row]+H1b[col]+rad*w1r) gathered directly (no GEMM1).
// Fused aggregation: per-block segmented reduction of ef over sorted rows
// (LDS transpose buffer overlaying Wbuf/ebuf) -> atomicAdd to global agg;
// trans summed directly via 3 atomics/edge into tsum. No k_agg pass.
// ---------------------------------------------------------------------------
__launch_bounds__(512,4)
__global__ void k_edge(const float* __restrict__ H1a,
                       const float* __restrict__ H1b,
                       const int* __restrict__ eidx,
                       const int* __restrict__ csr,
                       const float* __restrict__ coord,
                       const float* __restrict__ We1,
                       const float* __restrict__ be2,
                       const float* __restrict__ Watt,
                       const float* __restrict__ batt,
                       const float* __restrict__ bc1,
                       const float* __restrict__ Wc2,
                       const ushort_t* __restrict__ wpre,
                       float* __restrict__ ef_out,
                       float* __restrict__ agg,
                       float* __restrict__ tsum)
{
  __shared__ __align__(16) char smem[67072];
  ushort_t* Wbuf = (ushort_t*)smem;                 // 32KB weight tile
  ushort_t* ebuf = (ushort_t*)(smem + 32768);       // 32KB activation tile
  float (*dscr)[2] = (float(*)[2])(smem + 65536);   // 1KB cross-wave dots
  int* rowLDS = (int*)(smem + 66560);               // 512B row ids
  float* aggLDS = (float*)smem;                     // 64KB overlay (post-GEMM3)

  const int tid = threadIdx.x;
  const int wv = tid>>6, ln = tid&63;
  const int wm = wv&3, wn = wv>>2;
  const int q = ln>>4, s = ln&15;
  const int cbase = wn*64;
  const int eb0 = blockIdx.x*128;
  const int mb = wm*32;
  const int* rowI = eidx;
  const int* colI = eidx + EE;

  // geometry for trans: sorted edge eb0+mb+(ln&31)
  const int jg = eb0 + mb + (ln&31);
  const int og = csr[min(jg, EE-1)];
  const int rg = rowI[og], cg = colI[og];
  const float cdx = coord[rg*3+0]-coord[cg*3+0];
  const float cdy = coord[rg*3+1]-coord[cg*3+1];
  const float cdz = coord[rg*3+2]-coord[cg*3+2];

  // e1 rows for this lane: sorted edges eb0+mb+s (mt0), +16+s (mt1)
  const int o0 = csr[min(eb0+mb+s,    EE-1)];
  const int o1 = csr[min(eb0+mb+16+s, EE-1)];
  const int r0 = rowI[o0], c0 = colI[o0];
  const int r1 = rowI[o1], c1 = colI[o1];
  float rad[2];
  { float dx=coord[r0*3+0]-coord[c0*3+0], dy=coord[r0*3+1]-coord[c0*3+1],
          dz=coord[r0*3+2]-coord[c0*3+2];
    rad[0]=dx*dx+dy*dy+dz*dz; }
  { float dx=coord[r1*3+0]-coord[c1*3+0], dy=coord[r1*3+1]-coord[c1*3+1],
          dz=coord[r1*3+2]-coord[c1*3+2];
    rad[1]=dx*dx+dy*dy+dz*dz; }

  stage(wpre, 2, Wbuf, tid);         // W2 (natural k-order)

  // ---- e1 gather epilogue -> ebuf (natural k pack, XOR-swizzled) ----------
  {
    f32x4 w0[2], w1[2];
    #pragma unroll
    for (int gi=0; gi<2; ++gi){
      const int g = wn*8 + q*2 + gi;
      const f32x4* pw = (const f32x4*)(We1 + 256*DD + g*8);
      w0[gi]=pw[0]; w1[gi]=pw[1];
    }
    #pragma unroll
    for (int mt=0; mt<2; ++mt){
      const int nR = mt ? r1 : r0, nC = mt ? c1 : c0;
      const float rd = rad[mt];
      const int m = mb + mt*16 + s;
      #pragma unroll
      for (int gi=0; gi<2; ++gi){
        const int g = wn*8 + q*2 + gi;           // k-granule 0..15 (8 bf16 each)
        const f32x4* pa = (const f32x4*)(H1a + (size_t)nR*DD + g*8);
        const f32x4* pb = (const f32x4*)(H1b + (size_t)nC*DD + g*8);
        f32x4 a0=pa[0], a1=pa[1], bv0=pb[0], bv1=pb[1];
        short8 pk;
        #pragma unroll
        for (int t=0;t<4;++t){
          pk[t]   = (short)f2bf(siluf(a0[t]+bv0[t]+rd*w0[gi][t]));
          pk[t+4] = (short)f2bf(siluf(a1[t]+bv1[t]+rd*w1[gi][t]));
        }
        *(short8*)((char*)ebuf + m*256 + ((g*16) ^ ((m&7)<<4))) = pk;
      }
    }
  }

  f32x4 acc[2][4];
  zacc(acc);
  __syncthreads();                                        // B1: ebuf+W2 ready

  // ---- GEMM2: silu(e1@W2+be2); att dot needs both col halves ---------------
  gemm_lds16(ebuf, Wbuf, mb, cbase, q, s, acc);
  {
    float wa[4], bb[4];
    #pragma unroll
    for (int ct=0;ct<4;++ct){ wa[ct]=Watt[cbase+16*ct+s]; bb[ct]=be2[cbase+16*ct+s]; }
    #pragma unroll
    for (int mt=0;mt<2;++mt){
      #pragma unroll
      for (int r=0;r<4;++r){
        float p = 0.f;
        #pragma unroll
        for (int ct=0;ct<4;++ct){
          float v = siluf(acc[mt][ct][r] + bb[ct]);
          acc[mt][ct][r] = v;
          p += v*wa[ct];
        }
        p += __shfl_xor(p,1); p += __shfl_xor(p,2);
        p += __shfl_xor(p,4); p += __shfl_xor(p,8);
        if (s==0) dscr[mb + mt*16 + q*4 + r][wn] = p;
      }
    }
  }
  __syncthreads();                                        // B2: dscr ready
  stage(wpre, 3, Wbuf, tid);                              // Wc1 (sigma)
  {
    const float bat = batt[0];
    #pragma unroll
    for (int mt=0;mt<2;++mt){
      #pragma unroll
      for (int r=0;r<4;++r){
        int m = mb + mt*16 + q*4 + r;
        float att = sigm(dscr[m][0] + dscr[m][1] + bat);
        short4v pk;
        #pragma unroll
        for (int ct=0;ct<4;++ct){
          acc[mt][ct][r] *= att;
          pk[ct]=(short)f2bf(acc[mt][ct][r]);
        }
        *(short4v*)((char*)ebuf + m*256 + ((16*s+8*wn) ^ ((m&7)<<4))) = pk;
        int js = eb0 + m;
        if (js < EE){
          float* rp = ef_out + (size_t)csr[js]*DD + cbase + s;
          #pragma unroll
          for (int ct=0;ct<4;++ct) rp[16*ct] = acc[mt][ct][r];
        }
      }
    }
  }
  __syncthreads();                                        // B3: ebuf(ef)+Wc1 ready

  // ---- GEMM3 (separate accumulators; ef stays live in acc) -----------------
  f32x4 acc2[2][4];
  zacc(acc2);
  gemm_lds16(ebuf, Wbuf, mb, cbase, q, s, acc2);
  {
    float wc[4], bb[4];
    #pragma unroll
    for (int ct=0;ct<4;++ct){ wc[ct]=Wc2[cbase+16*ct+s]; bb[ct]=bc1[cbase+16*ct+s]; }
    #pragma unroll
    for (int mt=0;mt<2;++mt){
      #pragma unroll
      for (int r=0;r<4;++r){
        float p = 0.f;
        #pragma unroll
        for (int ct=0;ct<4;++ct) p += siluf(acc2[mt][ct][r]+bb[ct])*wc[ct];
        p += __shfl_xor(p,1); p += __shfl_xor(p,2);
        p += __shfl_xor(p,4); p += __shfl_xor(p,8);
        if (s==0) dscr[mb + mt*16 + q*4 + r][wn] = p;
      }
    }
  }
  __syncthreads();                                        // B4: dots ready; Wbuf/ebuf dead

  // ---- trans: direct global atomics (sorted rows -> L2-local) --------------
  if (wn==0 && ln<32){
    rowLDS[mb+ln] = rg;
    if (jg < EE){
      float p = dscr[mb+ln][0] + dscr[mb+ln][1];
      atomicAdd(&tsum[(size_t)rg*3+0], clamp10(cdx*p));
      atomicAdd(&tsum[(size_t)rg*3+1], clamp10(cdy*p));
      atomicAdd(&tsum[(size_t)rg*3+2], clamp10(cdz*p));
    }
  }

  // ---- ef transpose into aggLDS (overlay), fp32, XOR-swizzled --------------
  #pragma unroll
  for (int mt=0;mt<2;++mt){
    #pragma unroll
    for (int r=0;r<4;++r){
      const int m = mb + mt*16 + q*4 + r;
      char* base = (char*)aggLDS + m*512;
      #pragma unroll
      for (int ct=0;ct<4;++ct){
        const int c = cbase + 16*ct + s;
        *(float*)(base + ((c*4) ^ ((m&7)<<4))) = acc[mt][ct][r];
      }
    }
  }
  __syncthreads();                                        // B5: aggLDS+rowLDS ready

  // ---- segmented per-row reduction -> atomicAdd into agg -------------------
  {
    const int c = tid & 127;
    const int sub = tid >> 7;                    // 0..3, wave-uniform
    const int mmax = min(128, EE - eb0);
    const int m0 = sub*32;
    if (m0 < mmax){
      const int mend = min(m0+32, mmax);
      int currow = rowLDS[m0];
      float sum = 0.f;
      for (int m=m0; m<mend; ++m){
        int rr = rowLDS[m];
        float v = *(const float*)((const char*)aggLDS + m*512 + ((c*4) ^ ((m&7)<<4)));
        if (rr != currow){
          atomicAdd(&agg[(size_t)currow*DD + c], sum);
          sum = 0.f; currow = rr;
        }
        sum += v;
      }
      atomicAdd(&agg[(size_t)currow*DD + c], sum);
    }
  }
}

// ---------------------------------------------------------------------------
// Node MLP + finisher: h_out = h + silu([h,agg]@Wn1+bn1)@Wn2 + bn2
// and coord_out = coord + clip(tsum/deg).
// ---------------------------------------------------------------------------
__launch_bounds__(512,4)
__global__ void k_node(const float* __restrict__ h,
                       const float* __restrict__ agg,
                       const float* __restrict__ tsum,
                       const int* __restrict__ rowstart,
                       const float* __restrict__ coord,
                       const ushort_t* __restrict__ wpre,
                       const float* __restrict__ bn1,
                       const float* __restrict__ bn2,
                       float* __restrict__ hout,
                       float* __restrict__ coord_out)
{
  __shared__ ushort_t Wbuf[16384];
  __shared__ ushort_t ubuf[16384];
  const int tid = threadIdx.x;
  const int wv = tid>>6, ln = tid&63;
  const int wm = wv&3, wn = wv>>2;
  const int q = ln>>4, s = ln&15;
  const int cbase = wn*64;
  const int n0 = blockIdx.x*128;
  const int mb = wm*32;
  const int nd0 = min(n0 + mb + s,      NN-1);
  const int nd1 = min(n0 + mb + 16 + s, NN-1);

  // coord finisher (independent of GEMM path)
  if (tid < 128){
    int n = n0 + tid;
    if (n < NN){
      int dg = rowstart[n+1] - rowstart[n];
      float inv = 1.0f/(float)max(dg,1);
      #pragma unroll
      for (int d=0; d<3; ++d)
        coord_out[(size_t)n*3+d] = coord[(size_t)n*3+d]
                                 + clamp10(tsum[(size_t)n*3+d]*inv);
    }
  }

  f32x4 acc[2][4];
  short8 af[2][4];
  zacc(acc);

  // pass 1: A = h (convert fp32->bf16)
  #pragma unroll
  for (int kc=0;kc<4;++kc){
    af[0][kc] = ldcvt(h + (size_t)nd0*DD + kc*32 + q*8);
    af[1][kc] = ldcvt(h + (size_t)nd1*DD + kc*32 + q*8);
  }
  stage(wpre, 4, Wbuf, tid);
  __syncthreads();
  gemm_b16(af, Wbuf, cbase, q, s, acc);

  // pass 2: A = agg (fp32 -> bf16)
  #pragma unroll
  for (int kc=0;kc<4;++kc){
    af[0][kc] = ldcvt(agg + (size_t)nd0*DD + kc*32 + q*8);
    af[1][kc] = ldcvt(agg + (size_t)nd1*DD + kc*32 + q*8);
  }
  __syncthreads();
  stage(wpre, 5, Wbuf, tid);
  __syncthreads();
  gemm_b16(af, Wbuf, cbase, q, s, acc);

  // u = silu(acc + bn1) -> sigma-pack (own col half)
  {
    float bb[4];
    #pragma unroll
    for (int ct=0;ct<4;++ct) bb[ct]=bn1[cbase+16*ct+s];
    #pragma unroll
    for (int mt=0;mt<2;++mt){
      #pragma unroll
      for (int r=0;r<4;++r){
        int m = mb + mt*16 + q*4 + r;
        short4v pk;
        #pragma unroll
        for (int ct=0;ct<4;++ct) pk[ct]=(short)f2bf(siluf(acc[mt][ct][r]+bb[ct]));
        *(short4v*)((char*)ubuf + m*256 + ((16*s+8*wn) ^ ((m&7)<<4))) = pk;
      }
    }
  }
  zacc(acc);
  __syncthreads();
  stage(wpre, 6, Wbuf, tid);
  __syncthreads();

  gemm_lds16(ubuf, Wbuf, mb, cbase, q, s, acc);

  {
    float bb[4];
    #pragma unroll
    for (int ct=0;ct<4;++ct) bb[ct]=bn2[cbase+16*ct+s];
    #pragma unroll
    for (int mt=0;mt<2;++mt){
      #pragma unroll
      for (int r=0;r<4;++r){
        int n = n0 + mb + mt*16 + q*4 + r;
        if (n < NN){
          const float* hp = h + (size_t)n*DD + cbase + s;
          float* op = hout + (size_t)n*DD + cbase + s;
          #pragma unroll
          for (int ct=0;ct<4;++ct) op[16*ct] = hp[16*ct] + acc[mt][ct][r] + bb[ct];
        }
      }
    }
  }
}

// ---------------------------------------------------------------------------
extern "C" void kernel_launch(void* const* d_in, const int* in_sizes, int n_in,
                              void* d_out, int out_size, void* d_ws, size_t ws_size,
                              hipStream_t stream)
{
  const float* h    = (const float*)d_in[0];
  const int*   eidx = (const int*)  d_in[1];
  const float* coord= (const float*)d_in[2];
  const float* We1  = (const float*)d_in[3];
  const float* be1  = (const float*)d_in[4];
  const float* We2  = (const float*)d_in[5];
  const float* be2  = (const float*)d_in[6];
  const float* Watt = (const float*)d_in[7];
  const float* batt = (const float*)d_in[8];
  const float* Wc1  = (const float*)d_in[9];
  const float* bc1  = (const float*)d_in[10];
  const float* Wc2  = (const float*)d_in[11];
  const float* Wn1  = (const float*)d_in[12];
  const float* bn1  = (const float*)d_in[13];
  const float* Wn2  = (const float*)d_in[14];
  const float* bn2  = (const float*)d_in[15];

  float* hout     = (float*)d_out;
  float* coordout = hout + (size_t)NN*DD;              // +6,400,000
  float* efout    = coordout + (size_t)NN*3;           // +6,550,000

  char* ws = (char*)d_ws;
  float* tsum     = (float*)(ws);                       // N*3 f32   =    600,000 B
  float* agg      = (float*)(ws + 600000);              // N*128 f32 = 25,600,000 B
  int*   cnt      = (int*)  (ws + 26200000);            // N
  int*   cursor   = (int*)  (ws + 26400000);            // N
  int*   rowstart = (int*)  (ws + 26600000);            // N+1
  int*   csr      = (int*)  (ws + 26800064);            // E
  ushort_t* wpre  = (ushort_t*)(ws + 28800064);         // 7*32768 B -> 29,029,440
  float* H1a      = (float*)(ws + 29029440);            // N*128 f32
  float* H1b      = (float*)(ws + 54629440);            // N*128 f32 -> ends 80,229,440
  // scan temporaries alias the csr buffer (overwritten later by k_scatter)
  int*   bsum     = csr;                                // SCAN_B ints
  int*   boff     = csr + 256;                          // SCAN_B ints

  hipMemsetAsync(tsum, 0,   600000, stream);
  hipMemsetAsync(agg,  0, 25600000, stream);
  hipMemsetAsync(cnt,  0,   200000, stream);
  k_prep   <<<448, 256, 0, stream>>>(We1, We2, Wc1, Wn1, Wn2, wpre);
  k_count  <<<1954,256, 0, stream>>>(eidx, cnt);
  k_bsum   <<<196, 256, 0, stream>>>(cnt, bsum);
  k_bscan  <<<1,   256, 0, stream>>>(bsum, boff);
  k_rscan  <<<196, 256, 0, stream>>>(cnt, boff, rowstart, cursor);
  k_scatter<<<1954,256, 0, stream>>>(eidx, cursor, csr);
  k_pre1   <<<391, 512, 0, stream>>>(h, wpre, be1, H1a, H1b);
  k_edge   <<<3907,512, 0, stream>>>(H1a, H1b, eidx, csr, coord, We1, be2, Watt,
                                     batt, bc1, Wc2, wpre, efout, agg, tsum);
  k_node   <<<391, 512, 0, stream>>>(h, agg, tsum, rowstart, coord, wpre,
                                     bn1, bn2, hout, coordout);
}

// Round 4
// 627.238 us; speedup vs baseline: 1.1175x; 1.1175x over previous
//
#include <hip/hip_runtime.h>

typedef unsigned short ushort_t;
typedef __attribute__((ext_vector_type(8))) short short8;   // 8 bf16 = 4 VGPRs (MFMA A/B frag)
typedef __attribute__((ext_vector_type(4))) short short4v;  // 4 bf16 = 8B
typedef __attribute__((ext_vector_type(4))) float f32x4;    // MFMA C/D frag

#define NN 50000
#define EE 500000
#define DD 128
#define MAXT 10.0f

#define MFMA(a,b,c) __builtin_amdgcn_mfma_f32_16x16x32_bf16((a),(b),(c),0,0,0)

__device__ __forceinline__ ushort_t f2bf(float x){          // RNE float->bf16
  unsigned u = __float_as_uint(x);
  u += 0x7FFFu + ((u>>16)&1u);
  return (ushort_t)(u>>16);
}
__device__ __forceinline__ float bf2f(ushort_t u){
  return __uint_as_float(((unsigned)u)<<16);
}
__device__ __forceinline__ float sigm(float x){ return 1.0f/(1.0f+__expf(-x)); }
__device__ __forceinline__ float siluf(float x){ return x*sigm(x); }
__device__ __forceinline__ float clamp10(float x){ return fminf(fmaxf(x,-MAXT),MAXT); }

// load 8 consecutive fp32, convert to bf16x8 frag
__device__ __forceinline__ short8 ldcvt(const float* p){
  f32x4 x = *(const f32x4*)p;
  f32x4 y = *(const f32x4*)(p+4);
  short8 t;
  #pragma unroll
  for (int j=0;j<4;++j){ t[j]=(short)f2bf(x[j]); t[j+4]=(short)f2bf(y[j]); }
  return t;
}

// ---------------------------------------------------------------------------
// Weight prep: bf16, transposed to [n][k], XOR-swizzled rows.
// sigma-permute k for mats whose A-side comes from C-layout packs:
//   kidx = 8*(c&15) + (c>>4).
// mats: 0 W1a(nat)  1 W1b(nat)  2 W2(nat)  3 Wc1(sigma)  4 Wn1a(nat)
//       5 Wn1b(nat) 6 Wn2(sigma)
// ---------------------------------------------------------------------------
__global__ void k_prep(const float* __restrict__ We1, const float* __restrict__ We2,
                       const float* __restrict__ Wc1, const float* __restrict__ Wn1,
                       const float* __restrict__ Wn2, ushort_t* __restrict__ wpre)
{
  int idx = blockIdx.x*256 + threadIdx.x;
  if (idx >= 7*16384) return;
  int mat = idx >> 14;
  int loc = idx & 16383;
  int n = loc >> 7;
  int kidx = loc & 127;
  int ko = 16*(kidx&7) + (kidx>>3);
  float v;
  switch(mat){
    case 0: v = We1[kidx*DD + n]; break;
    case 1: v = We1[(128+kidx)*DD + n]; break;
    case 2: v = We2[kidx*DD + n]; break;           // natural
    case 3: v = Wc1[ko*DD + n]; break;             // sigma
    case 4: v = Wn1[kidx*DD + n]; break;
    case 5: v = Wn1[(128+kidx)*DD + n]; break;
    default: v = Wn2[ko*DD + n]; break;            // sigma
  }
  int byteoff = n*256 + ((kidx*2) ^ ((n&7)<<4));   // XOR swizzle (16B granule)
  *(ushort_t*)((char*)wpre + (size_t)mat*32768 + byteoff) = f2bf(v);
}

// ---------------------------------------------------------------------------
// CSR build (parallel scan; bsum/boff alias the csr buffer, overwritten later)
// ---------------------------------------------------------------------------
__global__ void k_count(const int* __restrict__ eidx, int* __restrict__ cnt){
  int e = blockIdx.x*256 + threadIdx.x;
  if (e < EE) atomicAdd(&cnt[eidx[e]], 1);
}
#define SCAN_B 196
__global__ void k_bsum(const int* __restrict__ cnt, int* __restrict__ bsum){
  __shared__ int sh[256];
  int t = threadIdx.x;
  int i = blockIdx.x*256 + t;
  sh[t] = (i < NN) ? cnt[i] : 0;
  __syncthreads();
  for (int off=128; off>0; off>>=1){
    if (t < off) sh[t] += sh[t+off];
    __syncthreads();
  }
  if (t==0) bsum[blockIdx.x] = sh[0];
}
__global__ void k_bscan(const int* __restrict__ bsum, int* __restrict__ boff){
  __shared__ int sh[256];
  int t = threadIdx.x;
  sh[t] = (t < SCAN_B) ? bsum[t] : 0;
  __syncthreads();
  for (int off=1; off<256; off<<=1){
    int x = (t>=off) ? sh[t-off] : 0;
    __syncthreads();
    sh[t] += x;
    __syncthreads();
  }
  if (t < SCAN_B) boff[t] = (t>0) ? sh[t-1] : 0;
}
__global__ void k_rscan(const int* __restrict__ cnt, const int* __restrict__ boff,
                        int* __restrict__ rowstart, int* __restrict__ cursor){
  __shared__ int sh[256];
  int t = threadIdx.x;
  int i = blockIdx.x*256 + t;
  int v = (i < NN) ? cnt[i] : 0;
  sh[t] = v;
  __syncthreads();
  for (int off=1; off<256; off<<=1){
    int x = (t>=off) ? sh[t-off] : 0;
    __syncthreads();
    sh[t] += x;
    __syncthreads();
  }
  int excl = sh[t] - v + boff[blockIdx.x];
  if (i < NN){ rowstart[i] = excl; cursor[i] = excl; }
  if (i == 0) rowstart[NN] = EE;
}
__global__ void k_scatter(const int* __restrict__ eidx, int* __restrict__ cursor,
                          int* __restrict__ csr){
  int e = blockIdx.x*256 + threadIdx.x;
  if (e < EE){
    int p = atomicAdd(&cursor[eidx[e]], 1);
    csr[p] = e;
  }
}

// ---------------------------------------------------------------------------
// GEMM helpers: wave tile = 32 rows x 64 cols x K=128.
// ---------------------------------------------------------------------------
__device__ __forceinline__ void stage(const ushort_t* __restrict__ wpre, int mat,
                                      ushort_t* Wbuf, int tid)
{
  const f32x4* src = (const f32x4*)(wpre + (size_t)mat*16384);
  f32x4* dst = (f32x4*)Wbuf;
  #pragma unroll
  for (int i=0;i<4;++i) dst[tid + 512*i] = src[tid + 512*i];
}
__device__ __forceinline__ void zacc(f32x4 acc[2][4]){
  #pragma unroll
  for (int i=0;i<2;++i)
    #pragma unroll
    for (int j=0;j<4;++j) acc[i][j] = (f32x4){0.f,0.f,0.f,0.f};
}
__device__ __forceinline__ void gemm_b16(const short8 af[2][4], const ushort_t* Wbuf,
                                         int cbase, int q, int s, f32x4 acc[2][4])
{
  #pragma unroll
  for (int kc=0;kc<4;++kc){
    const int koff = ((kc*64+q*16) ^ ((s&7)<<4));
    #pragma unroll
    for (int ct=0;ct<4;++ct){
      short8 bf = *(const short8*)((const char*)Wbuf + (cbase+ct*16+s)*256 + koff);
      acc[0][ct] = MFMA(af[0][kc],bf,acc[0][ct]);
      acc[1][ct] = MFMA(af[1][kc],bf,acc[1][ct]);
    }
  }
}
__device__ __forceinline__ void gemm_lds16(const ushort_t* ebuf, const ushort_t* Wbuf,
                                           int mbase, int cbase, int q, int s,
                                           f32x4 acc[2][4])
{
  #pragma unroll
  for (int kc=0;kc<4;++kc){
    const int koff = ((kc*64+q*16) ^ ((s&7)<<4));
    short8 a0 = *(const short8*)((const char*)ebuf + (mbase+s)*256 + koff);
    short8 a1 = *(const short8*)((const char*)ebuf + (mbase+16+s)*256 + koff);
    #pragma unroll
    for (int ct=0;ct<4;++ct){
      short8 bf = *(const short8*)((const char*)Wbuf + (cbase+ct*16+s)*256 + koff);
      acc[0][ct] = MFMA(a0,bf,acc[0][ct]);
      acc[1][ct] = MFMA(a1,bf,acc[1][ct]);
    }
  }
}

// ---------------------------------------------------------------------------
// H1 precompute: H1a = h@W1a + be1 ; H1b = h@W1b   (bf16 out, N x 128 each)
// ---------------------------------------------------------------------------
__launch_bounds__(512,4)
__global__ void k_pre1(const float* __restrict__ h,
                       const ushort_t* __restrict__ wpre,
                       const float* __restrict__ be1,
                       ushort_t* __restrict__ H1a, ushort_t* __restrict__ H1b)
{
  __shared__ ushort_t Wbuf[16384];
  const int tid = threadIdx.x;
  const int wv = tid>>6, ln = tid&63;
  const int wm = wv&3, wn = wv>>2;
  const int q = ln>>4, s = ln&15;
  const int cbase = wn*64;
  const int n0 = blockIdx.x*128;
  const int mb = wm*32;
  const int nd0 = min(n0 + mb + s,      NN-1);
  const int nd1 = min(n0 + mb + 16 + s, NN-1);

  f32x4 acc[2][4];
  short8 af[2][4];
  zacc(acc);
  #pragma unroll
  for (int kc=0;kc<4;++kc){
    af[0][kc] = ldcvt(h + (size_t)nd0*DD + kc*32 + q*8);
    af[1][kc] = ldcvt(h + (size_t)nd1*DD + kc*32 + q*8);
  }
  stage(wpre, 0, Wbuf, tid);
  __syncthreads();
  gemm_b16(af, Wbuf, cbase, q, s, acc);
  {
    float bb[4];
    #pragma unroll
    for (int ct=0;ct<4;++ct) bb[ct]=be1[cbase+16*ct+s];
    #pragma unroll
    for (int mt=0;mt<2;++mt)
      #pragma unroll
      for (int r=0;r<4;++r){
        int n = n0 + mb + mt*16 + q*4 + r;
        if (n < NN){
          ushort_t* op = H1a + (size_t)n*DD + cbase + s;
          #pragma unroll
          for (int ct=0;ct<4;++ct) op[16*ct] = f2bf(acc[mt][ct][r] + bb[ct]);
        }
      }
  }
  zacc(acc);
  __syncthreads();
  stage(wpre, 1, Wbuf, tid);
  __syncthreads();
  gemm_b16(af, Wbuf, cbase, q, s, acc);
  {
    #pragma unroll
    for (int mt=0;mt<2;++mt)
      #pragma unroll
      for (int r=0;r<4;++r){
        int n = n0 + mb + mt*16 + q*4 + r;
        if (n < NN){
          ushort_t* op = H1b + (size_t)n*DD + cbase + s;
          #pragma unroll
          for (int ct=0;ct<4;++ct) op[16*ct] = f2bf(acc[mt][ct][r]);
        }
      }
  }
}

// ---------------------------------------------------------------------------
// Edge kernel (natural order): 128 edges/block, 8 waves 4(M) x 2(N).
// e1 = silu(H1a[row]+H1b[col]+rad*w1r) gathered from bf16 H1 (no GEMM1).
// ---------------------------------------------------------------------------
__launch_bounds__(512,4)
__global__ void k_edge(const ushort_t* __restrict__ H1a,
                       const ushort_t* __restrict__ H1b,
                       const int* __restrict__ eidx,
                       const float* __restrict__ coord,
                       const float* __restrict__ We1,
                       const float* __restrict__ be2,
                       const float* __restrict__ Watt,
                       const float* __restrict__ batt,
                       const float* __restrict__ bc1,
                       const float* __restrict__ Wc2,
                       const ushort_t* __restrict__ wpre,
                       float* __restrict__ ef_out,
                       float* __restrict__ trans)
{
  __shared__ ushort_t Wbuf[16384];   // 32KB weight tile [n][k] swizzled
  __shared__ ushort_t ebuf[16384];   // 32KB activation tile
  __shared__ float dscr[128][2];     // cross-wave row-dot partials (1KB)
  const int tid = threadIdx.x;
  const int wv = tid>>6, ln = tid&63;
  const int wm = wv&3, wn = wv>>2;
  const int q = ln>>4, s = ln&15;
  const int cbase = wn*64;
  const int we0 = blockIdx.x*128;
  const int mb = wm*32;
  const int* rowI = eidx;
  const int* colI = eidx + EE;

  // geometry for trans write: edge we0+mb+(ln&31) (natural order)
  const int jg = we0 + mb + (ln&31);
  const int jgc = min(jg, EE-1);
  const int rg = rowI[jgc], cg = colI[jgc];
  const float cdx = coord[rg*3+0]-coord[cg*3+0];
  const float cdy = coord[rg*3+1]-coord[cg*3+1];
  const float cdz = coord[rg*3+2]-coord[cg*3+2];

  // e1 rows for this lane: edges we0+mb+s (mt0), +16+s (mt1)
  const int e0 = min(we0+mb+s,    EE-1);
  const int e1 = min(we0+mb+16+s, EE-1);
  const int r0 = rowI[e0], c0 = colI[e0];
  const int r1 = rowI[e1], c1 = colI[e1];
  float rad[2];
  { float dx=coord[r0*3+0]-coord[c0*3+0], dy=coord[r0*3+1]-coord[c0*3+1],
          dz=coord[r0*3+2]-coord[c0*3+2];
    rad[0]=dx*dx+dy*dy+dz*dz; }
  { float dx=coord[r1*3+0]-coord[c1*3+0], dy=coord[r1*3+1]-coord[c1*3+1],
          dz=coord[r1*3+2]-coord[c1*3+2];
    rad[1]=dx*dx+dy*dy+dz*dz; }

  stage(wpre, 2, Wbuf, tid);         // W2 (natural k-order)

  // ---- e1 gather epilogue -> ebuf (natural k pack, XOR-swizzled) ----------
  {
    float w[2][8];
    #pragma unroll
    for (int gi=0; gi<2; ++gi){
      const int g = wn*8 + q*2 + gi;
      const f32x4* pw = (const f32x4*)(We1 + 256*DD + g*8);
      f32x4 w0=pw[0], w1=pw[1];
      #pragma unroll
      for (int t=0;t<4;++t){ w[gi][t]=w0[t]; w[gi][t+4]=w1[t]; }
    }
    #pragma unroll
    for (int mt=0; mt<2; ++mt){
      const int nR = mt ? r1 : r0, nC = mt ? c1 : c0;
      const float rd = rad[mt];
      const int m = mb + mt*16 + s;
      #pragma unroll
      for (int gi=0; gi<2; ++gi){
        const int g = wn*8 + q*2 + gi;           // k-granule 0..15 (8 bf16 each)
        short8 sa = *(const short8*)(H1a + (size_t)nR*DD + g*8);
        short8 sb = *(const short8*)(H1b + (size_t)nC*DD + g*8);
        short8 pk;
        #pragma unroll
        for (int t=0;t<8;++t){
          float e = bf2f((ushort_t)sa[t]) + bf2f((ushort_t)sb[t]) + rd*w[gi][t];
          pk[t] = (short)f2bf(siluf(e));
        }
        *(short8*)((char*)ebuf + m*256 + ((g*16) ^ ((m&7)<<4))) = pk;
      }
    }
  }

  f32x4 acc[2][4];
  zacc(acc);
  __syncthreads();                                        // B1: ebuf+W2 ready

  // ---- GEMM2: silu(e1@W2+be2); att dot needs both col halves ---------------
  gemm_lds16(ebuf, Wbuf, mb, cbase, q, s, acc);
  {
    float wa[4], bb[4];
    #pragma unroll
    for (int ct=0;ct<4;++ct){ wa[ct]=Watt[cbase+16*ct+s]; bb[ct]=be2[cbase+16*ct+s]; }
    #pragma unroll
    for (int mt=0;mt<2;++mt){
      #pragma unroll
      for (int r=0;r<4;++r){
        float p = 0.f;
        #pragma unroll
        for (int ct=0;ct<4;++ct){
          float v = siluf(acc[mt][ct][r] + bb[ct]);
          acc[mt][ct][r] = v;
          p += v*wa[ct];
        }
        p += __shfl_xor(p,1); p += __shfl_xor(p,2);
        p += __shfl_xor(p,4); p += __shfl_xor(p,8);
        if (s==0) dscr[mb + mt*16 + q*4 + r][wn] = p;
      }
    }
  }
  __syncthreads();                                        // B2: dscr ready
  stage(wpre, 3, Wbuf, tid);                              // Wc1 (sigma)
  {
    const float bat = batt[0];
    #pragma unroll
    for (int mt=0;mt<2;++mt){
      #pragma unroll
      for (int r=0;r<4;++r){
        int m = mb + mt*16 + q*4 + r;
        float att = sigm(dscr[m][0] + dscr[m][1] + bat);
        short4v pk;
        #pragma unroll
        for (int ct=0;ct<4;++ct){
          acc[mt][ct][r] *= att;
          pk[ct]=(short)f2bf(acc[mt][ct][r]);
        }
        *(short4v*)((char*)ebuf + m*256 + ((16*s+8*wn) ^ ((m&7)<<4))) = pk;
        int e = we0 + m;
        if (e < EE){
          float* rp = ef_out + (size_t)e*DD + cbase + s;
          #pragma unroll
          for (int ct=0;ct<4;++ct) rp[16*ct] = acc[mt][ct][r];
        }
      }
    }
  }
  zacc(acc);
  __syncthreads();                                        // B3: ebuf(ef)+Wc1 ready

  // ---- GEMM3: cw = silu(ef@Wc1+bc1)@Wc2 ; trans = clip(cdiff*cw) -----------
  gemm_lds16(ebuf, Wbuf, mb, cbase, q, s, acc);
  {
    float wc[4], bb[4];
    #pragma unroll
    for (int ct=0;ct<4;++ct){ wc[ct]=Wc2[cbase+16*ct+s]; bb[ct]=bc1[cbase+16*ct+s]; }
    #pragma unroll
    for (int mt=0;mt<2;++mt){
      #pragma unroll
      for (int r=0;r<4;++r){
        float p = 0.f;
        #pragma unroll
        for (int ct=0;ct<4;++ct) p += siluf(acc[mt][ct][r]+bb[ct])*wc[ct];
        p += __shfl_xor(p,1); p += __shfl_xor(p,2);
        p += __shfl_xor(p,4); p += __shfl_xor(p,8);
        if (s==0) dscr[mb + mt*16 + q*4 + r][wn] = p;
      }
    }
  }
  __syncthreads();                                        // B4
  if (wn==0 && ln<32 && jg < EE){
    float p = dscr[mb+ln][0] + dscr[mb+ln][1];
    trans[(size_t)jg*3+0] = clamp10(cdx*p);
    trans[(size_t)jg*3+1] = clamp10(cdy*p);
    trans[(size_t)jg*3+2] = clamp10(cdz*p);
  }
}

// ---------------------------------------------------------------------------
// Node aggregation (atomic-free via CSR): agg (bf16 out), coord_out
// ---------------------------------------------------------------------------
__launch_bounds__(256)
__global__ void k_agg(const float* __restrict__ ef,
                      const float* __restrict__ trans,
                      const int* __restrict__ rowstart,
                      const int* __restrict__ csr,
                      const float* __restrict__ coord,
                      ushort_t* __restrict__ aggb,
                      float* __restrict__ coord_out)
{
  const int wv = threadIdx.x>>6, ln = threadIdx.x&63;
  const int n = blockIdx.x*4 + wv;
  if (n >= NN) return;
  const int rs = rowstart[n], re = rowstart[n+1];
  const int deg = re - rs;
  const int half = ln>>5, l4 = (ln&31)*4;
  float a0=0,a1=0,a2=0,a3=0;
  for (int j=half; j<deg; j+=2){
    const float* p = ef + (size_t)csr[rs+j]*DD + l4;
    f32x4 v = *(const f32x4*)p;
    a0+=v[0]; a1+=v[1]; a2+=v[2]; a3+=v[3];
  }
  a0 += __shfl_xor(a0,32); a1 += __shfl_xor(a1,32);
  a2 += __shfl_xor(a2,32); a3 += __shfl_xor(a3,32);
  if (half==0){
    short4v o = { (short)f2bf(a0),(short)f2bf(a1),(short)f2bf(a2),(short)f2bf(a3) };
    *(short4v*)(aggb + (size_t)n*DD + l4) = o;
  }
  float tx=0,ty=0,tz=0;
  for (int j=ln;j<deg;j+=64){
    const float* t = trans + (size_t)csr[rs+j]*3;
    tx+=t[0]; ty+=t[1]; tz+=t[2];
  }
  #pragma unroll
  for (int m=1;m<64;m<<=1){
    tx+=__shfl_xor(tx,m); ty+=__shfl_xor(ty,m); tz+=__shfl_xor(tz,m);
  }
  if (ln==0){
    const float inv = 1.0f/(float)max(deg,1);
    coord_out[(size_t)n*3+0] = coord[(size_t)n*3+0] + clamp10(tx*inv);
    coord_out[(size_t)n*3+1] = coord[(size_t)n*3+1] + clamp10(ty*inv);
    coord_out[(size_t)n*3+2] = coord[(size_t)n*3+2] + clamp10(tz*inv);
  }
}

// ---------------------------------------------------------------------------
// Node MLP: h_out = h + silu([h,agg]@Wn1+bn1)@Wn2 + bn2
// ---------------------------------------------------------------------------
__launch_bounds__(512,4)
__global__ void k_node(const float* __restrict__ h,
                       const ushort_t* __restrict__ aggb,
                       const ushort_t* __restrict__ wpre,
                       const float* __restrict__ bn1,
                       const float* __restrict__ bn2,
                       float* __restrict__ hout)
{
  __shared__ ushort_t Wbuf[16384];
  __shared__ ushort_t ubuf[16384];
  const int tid = threadIdx.x;
  const int wv = tid>>6, ln = tid&63;
  const int wm = wv&3, wn = wv>>2;
  const int q = ln>>4, s = ln&15;
  const int cbase = wn*64;
  const int n0 = blockIdx.x*128;
  const int mb = wm*32;
  const int nd0 = min(n0 + mb + s,      NN-1);
  const int nd1 = min(n0 + mb + 16 + s, NN-1);

  f32x4 acc[2][4];
  short8 af[2][4];
  zacc(acc);

  // pass 1: A = h (convert fp32->bf16)
  #pragma unroll
  for (int kc=0;kc<4;++kc){
    af[0][kc] = ldcvt(h + (size_t)nd0*DD + kc*32 + q*8);
    af[1][kc] = ldcvt(h + (size_t)nd1*DD + kc*32 + q*8);
  }
  stage(wpre, 4, Wbuf, tid);
  __syncthreads();
  gemm_b16(af, Wbuf, cbase, q, s, acc);

  // pass 2: A = agg (bf16 direct)
  #pragma unroll
  for (int kc=0;kc<4;++kc){
    af[0][kc] = *(const short8*)(aggb + (size_t)nd0*DD + kc*32 + q*8);
    af[1][kc] = *(const short8*)(aggb + (size_t)nd1*DD + kc*32 + q*8);
  }
  __syncthreads();
  stage(wpre, 5, Wbuf, tid);
  __syncthreads();
  gemm_b16(af, Wbuf, cbase, q, s, acc);

  // u = silu(acc + bn1) -> sigma-pack (own col half)
  {
    float bb[4];
    #pragma unroll
    for (int ct=0;ct<4;++ct) bb[ct]=bn1[cbase+16*ct+s];
    #pragma unroll
    for (int mt=0;mt<2;++mt){
      #pragma unroll
      for (int r=0;r<4;++r){
        int m = mb + mt*16 + q*4 + r;
        short4v pk;
        #pragma unroll
        for (int ct=0;ct<4;++ct) pk[ct]=(short)f2bf(siluf(acc[mt][ct][r]+bb[ct]));
        *(short4v*)((char*)ubuf + m*256 + ((16*s+8*wn) ^ ((m&7)<<4))) = pk;
      }
    }
  }
  zacc(acc);
  __syncthreads();
  stage(wpre, 6, Wbuf, tid);
  __syncthreads();

  gemm_lds16(ubuf, Wbuf, mb, cbase, q, s, acc);

  {
    float bb[4];
    #pragma unroll
    for (int ct=0;ct<4;++ct) bb[ct]=bn2[cbase+16*ct+s];
    #pragma unroll
    for (int mt=0;mt<2;++mt){
      #pragma unroll
      for (int r=0;r<4;++r){
        int n = n0 + mb + mt*16 + q*4 + r;
        if (n < NN){
          const float* hp = h + (size_t)n*DD + cbase + s;
          float* op = hout + (size_t)n*DD + cbase + s;
          #pragma unroll
          for (int ct=0;ct<4;++ct) op[16*ct] = hp[16*ct] + acc[mt][ct][r] + bb[ct];
        }
      }
    }
  }
}

// ---------------------------------------------------------------------------
extern "C" void kernel_launch(void* const* d_in, const int* in_sizes, int n_in,
                              void* d_out, int out_size, void* d_ws, size_t ws_size,
                              hipStream_t stream)
{
  const float* h    = (const float*)d_in[0];
  const int*   eidx = (const int*)  d_in[1];
  const float* coord= (const float*)d_in[2];
  const float* We1  = (const float*)d_in[3];
  const float* be1  = (const float*)d_in[4];
  const float* We2  = (const float*)d_in[5];
  const float* be2  = (const float*)d_in[6];
  const float* Watt = (const float*)d_in[7];
  const float* batt = (const float*)d_in[8];
  const float* Wc1  = (const float*)d_in[9];
  const float* bc1  = (const float*)d_in[10];
  const float* Wc2  = (const float*)d_in[11];
  const float* Wn1  = (const float*)d_in[12];
  const float* bn1  = (const float*)d_in[13];
  const float* Wn2  = (const float*)d_in[14];
  const float* bn2  = (const float*)d_in[15];

  float* hout     = (float*)d_out;
  float* coordout = hout + (size_t)NN*DD;              // +6,400,000
  float* efout    = coordout + (size_t)NN*3;           // +6,550,000

  char* ws = (char*)d_ws;
  float*    trans = (float*)(ws);                       // E*3 f32    =  6,000,000 B
  ushort_t* aggb  = (ushort_t*)(ws + 6000000);          // N*128 bf16 = 12,800,000 B
  int*   cnt      = (int*)  (ws + 18800000);            // N
  int*   cursor   = (int*)  (ws + 19000000);            // N
  int*   rowstart = (int*)  (ws + 19200000);            // N+1
  int*   csr      = (int*)  (ws + 19400064);            // E
  ushort_t* wpre  = (ushort_t*)(ws + 21400064);         // 7*32768 B -> 21,629,440
  ushort_t* H1a   = (ushort_t*)(ws + 21629440);         // N*128 bf16 = 12,800,000 B
  ushort_t* H1b   = (ushort_t*)(ws + 34429440);         // N*128 bf16 -> ends 47,229,440
  // scan temporaries alias the csr buffer (overwritten later by k_scatter)
  int*   bsum     = csr;                                // SCAN_B ints
  int*   boff     = csr + 256;                          // SCAN_B ints

  hipMemsetAsync(cnt, 0, 200000, stream);
  k_prep   <<<448, 256, 0, stream>>>(We1, We2, Wc1, Wn1, Wn2, wpre);
  k_count  <<<1954,256, 0, stream>>>(eidx, cnt);
  k_bsum   <<<196, 256, 0, stream>>>(cnt, bsum);
  k_bscan  <<<1,   256, 0, stream>>>(bsum, boff);
  k_rscan  <<<196, 256, 0, stream>>>(cnt, boff, rowstart, cursor);
  k_scatter<<<1954,256, 0, stream>>>(eidx, cursor, csr);
  k_pre1   <<<391, 512, 0, stream>>>(h, wpre, be1, H1a, H1b);
  k_edge   <<<3907,512, 0, stream>>>(H1a, H1b, eidx, coord, We1, be2, Watt,
                                     batt, bc1, Wc2, wpre, efout, trans);
  k_agg    <<<12500,256,0, stream>>>(efout, trans, rowstart, csr, coord, aggb, coordout);
  k_node   <<<391, 512, 0, stream>>>(h, aggb, wpre, bn1, bn2, hout);
}